// Round 2
// baseline (201.868 us; speedup 1.0000x reference)
//
#include <hip/hip_runtime.h>
#include <stdint.h>

// Problem constants: N=128, T=2048, D=88
#define NN 128
#define TT 2048
#define DD 88
#define ROWS 32                      // timesteps per K1 block
#define F4_ROW 22                    // float4 per row (88 floats)
#define K1_BLOCKS (NN * TT / ROWS)   // 8192
#define PARTS_PER_N (TT / ROWS)      // 64 tp partials per n
#define CPN 8                        // tail chunk-blocks per n
#define K2_BLOCKS (NN * CPN)         // 1024

typedef float f4 __attribute__((ext_vector_type(4)));

// K1 (rebuilt, direct-to-register): previous structure staged via
// global_load_lds + full vmcnt(0) drain at a barrier (the documented ~20%
// barrier-drain stall) and capped at 6 blocks/CU by 23KB LDS (55% occupancy).
// The 8-threads-per-row consume pattern doesn't need LDS at all: for fixed
// j0, a wave's 64 lanes read 8x 128B segments dense within a contiguous
// 2816B span -- full cacheline coverage from plain dwordx4 loads.
// This version: zero LDS tile, no staging barrier, 6 independent 16B loads
// per thread issued up-front, compiler-scheduled fine-grained vmcnt.
// Expected: occupancy ~2x (more outstanding bytes/CU), no collective drain.
__global__ __launch_bounds__(256) void acc_rowstats_kernel(
    const float* __restrict__ outp, const float* __restrict__ tgt,
    float* __restrict__ fpfn, float* __restrict__ tp_part) {
  __shared__ float s_tp[4];

  const int tid = threadIdx.x;
  const int lane = tid & 63;
  const int wave = tid >> 6;
  const int blk = blockIdx.x;
  const size_t base = (size_t)blk * (ROWS * DD);  // element offset of tile

  const int r = tid >> 3;  // 0..31 : row within tile
  const int s = tid & 7;   // 0..7  : f4 slot group within row

  const f4* o4 = (const f4*)(outp + base) + (size_t)r * F4_ROW;
  const f4* g4 = (const f4*)(tgt + base) + (size_t)r * F4_ROW;

  // Unconditional loads so the scheduler hoists all 6 before compute.
  // Third slot (j = s+16) is only valid for s<6; lanes s>=6 re-read slot s
  // (same cachelines, L1-hit) and their contribution is masked out below.
  const int j2 = (s < 6) ? (s + 16) : s;
  const f4 o0 = o4[s];
  const f4 g0 = g4[s];
  const f4 o1 = o4[s + 8];
  const f4 g1 = g4[s + 8];
  const f4 o2 = o4[j2];
  const f4 g2 = g4[j2];

  float x = 0.f, tp = 0.f;    // fp+fn and tp accumulators (slots 0,1)
  float x2 = 0.f, tp2 = 0.f;  // slot 2 (masked)

#define ACC1(ov, gv, xa, ta)                        \
  do {                                              \
    const float pf = ((ov) > 0.f) ? 1.f : 0.f;      \
    (xa) += fabsf(pf - (gv));                       \
    (ta) = fmaf(pf, (gv), (ta));                    \
  } while (0)

  ACC1(o0.x, g0.x, x, tp); ACC1(o0.y, g0.y, x, tp);
  ACC1(o0.z, g0.z, x, tp); ACC1(o0.w, g0.w, x, tp);
  ACC1(o1.x, g1.x, x, tp); ACC1(o1.y, g1.y, x, tp);
  ACC1(o1.z, g1.z, x, tp); ACC1(o1.w, g1.w, x, tp);
  ACC1(o2.x, g2.x, x2, tp2); ACC1(o2.y, g2.y, x2, tp2);
  ACC1(o2.z, g2.z, x2, tp2); ACC1(o2.w, g2.w, x2, tp2);
#undef ACC1

  if (s < 6) { x += x2; tp += tp2; }

  // fpfn: reduce across the 8 contiguous lanes of this row
  x += __shfl_down(x, 4, 64);
  x += __shfl_down(x, 2, 64);
  x += __shfl_down(x, 1, 64);
  if (s == 0) fpfn[(size_t)blk * ROWS + r] = x;

  // tp: wave reduce + cross-wave, deterministic per-block partial
  for (int off = 32; off > 0; off >>= 1) tp += __shfl_down(tp, off, 64);
  if (lane == 0) s_tp[wave] = tp;
  __syncthreads();
  if (tid == 0) tp_part[blk] = s_tp[0] + s_tp[1] + s_tp[2] + s_tp[3];
}

// K2: 8 chunk-blocks per n; all global loads issue before any reduction;
// Ti/tp are exact-integer sums (order-insensitive); 2 barriers; no atomics.
// UNCHANGED this round (tail proven ~free; isolates the K1 variable).
__global__ __launch_bounds__(256) void acc_chunk_kernel(
    const int* __restrict__ mask, const float* __restrict__ fpfn,
    const float* __restrict__ tp_part, float* __restrict__ accp) {
  const int b = blockIdx.x;
  const int n = b >> 3;            // CPN = 8
  const int c = b & (CPN - 1);
  const int tid = threadIdx.x;
  const int lane = tid & 63;
  const int wave = tid >> 6;
  __shared__ float s_ti[4];
  __shared__ float s_tp[4];
  __shared__ float s_a[4];

  // ---- issue every global load up front (nothing gated on reductions) ----
  const int4* m4 = (const int4*)(mask + (size_t)n * TT);
  const int4 v0 = m4[tid];
  const int4 v1 = m4[tid + 256];
  const float tpv = (tid < PARTS_PER_N) ? tp_part[n * PARTS_PER_N + tid] : 0.f;
  const int t = c * 256 + tid;
  const float fr = fpfn[(size_t)n * TT + t];

  // ---- Ti and tp: exact-integer shuffle reductions (order-insensitive) ----
  int ti = v0.x + v0.y + v0.z + v0.w + v1.x + v1.y + v1.z + v1.w;
  float tp = tpv;
  for (int off = 32; off > 0; off >>= 1) {
    ti += __shfl_down(ti, off, 64);
    tp += __shfl_down(tp, off, 64);
  }
  if (lane == 0) { s_ti[wave] = (float)ti; s_tp[wave] = tp; }
  __syncthreads();
  const float fTi = s_ti[0] + s_ti[1] + s_ti[2] + s_ti[3];  // exact (<= 2048)
  const float tpn = s_tp[0] + s_tp[1] + s_tp[2] + s_tp[3];  // exact integer
  const int Ti = (int)fTi;

  // ---- ratio for this block's 256 timesteps, then block reduction ----
  float a = (t < Ti) ? tpn / (tpn + fr) : 0.f;
  for (int off = 32; off > 0; off >>= 1) a += __shfl_down(a, off, 64);
  if (lane == 0) s_a[wave] = a;
  __syncthreads();
  if (tid == 0)
    accp[b] = (s_a[0] + s_a[1] + s_a[2] + s_a[3]) / fTi;
}

// K3: deterministic final sum of the 1024 chunk partials -> out[0].
__global__ __launch_bounds__(256) void acc_sum_kernel(
    const float* __restrict__ accp, float* __restrict__ out) {
  const int tid = threadIdx.x;
  const int lane = tid & 63;
  const int wave = tid >> 6;
  __shared__ float s_a[4];
  float a = accp[tid] + accp[tid + 256] + accp[tid + 512] + accp[tid + 768];
  for (int off = 32; off > 0; off >>= 1) a += __shfl_down(a, off, 64);
  if (lane == 0) s_a[wave] = a;
  __syncthreads();
  if (tid == 0) out[0] = s_a[0] + s_a[1] + s_a[2] + s_a[3];
}

extern "C" void kernel_launch(void* const* d_in, const int* in_sizes, int n_in,
                              void* d_out, int out_size, void* d_ws, size_t ws_size,
                              hipStream_t stream) {
  const float* output = (const float*)d_in[0];
  const float* target = (const float*)d_in[1];
  const int* mask = (const int*)d_in[2];
  float* out = (float*)d_out;

  float* tp_part = (float*)d_ws;          // K1_BLOCKS floats
  float* fpfn = tp_part + K1_BLOCKS;      // N*T floats
  float* accp = fpfn + (size_t)NN * TT;   // K2_BLOCKS floats

  acc_rowstats_kernel<<<K1_BLOCKS, 256, 0, stream>>>(output, target, fpfn, tp_part);
  acc_chunk_kernel<<<K2_BLOCKS, 256, 0, stream>>>(mask, fpfn, tp_part, accp);
  acc_sum_kernel<<<1, 256, 0, stream>>>(accp, out);
}